// Round 1
// baseline (1916.255 us; speedup 1.0000x reference)
//
#include <hip/hip_runtime.h>

// MoE top-2 of 8 experts. T=4096 tokens, D=1024, F=3584.
// Pipeline: router+gather -> per-expert [GEMM1(SwiGLU fused) -> GEMM2(scatter)].
// GEMMs: bf16 MFMA 16x16x32, 128x128x32 tiles, 4 waves of 4x4 acc tiles.

#define T_TOK 4096
#define D_DIM 1024
#define F_DIM 3584
#define E_NUM 8
#define N13   (2 * F_DIM)   // 7168: w1/w3 interleaved in 16-row blocks
#define BM 128
#define BN 128
#define BK 32

typedef __bf16 bf16x8 __attribute__((ext_vector_type(8)));
typedef float  f32x4  __attribute__((ext_vector_type(4)));

__device__ __forceinline__ unsigned f2bf_u(float f) {
    unsigned u = __builtin_bit_cast(unsigned, f);
    return (u + 0x7FFFu + ((u >> 16) & 1u)) >> 16;   // RNE
}
__device__ __forceinline__ unsigned pack2(float lo, float hi) {
    return f2bf_u(lo) | (f2bf_u(hi) << 16);
}

// ---------------------------------------------------------------------------
// Router + gather: 1 wave per token (block = 4 waves).
// Writes fp32 logits, builds per-expert compacted bf16 token rows (x * weight).
// ---------------------------------------------------------------------------
__global__ __launch_bounds__(256)
void router_gather(const float* __restrict__ x, const float* __restrict__ gw,
                   float* __restrict__ logits, int* __restrict__ counts,
                   int* __restrict__ tok, unsigned short* __restrict__ Xe)
{
    const int wave = threadIdx.x >> 6;
    const int lane = threadIdx.x & 63;
    const int t = blockIdx.x * 4 + wave;

    const float* xt = x + (size_t)t * D_DIM + lane * 16;
    float4 xv[4];
#pragma unroll
    for (int i = 0; i < 4; i++) xv[i] = ((const float4*)xt)[i];

    float l[E_NUM];
#pragma unroll
    for (int e = 0; e < E_NUM; e++) {
        const float4* gp = (const float4*)(gw + (size_t)e * D_DIM + lane * 16);
        float d = 0.f;
#pragma unroll
        for (int i = 0; i < 4; i++) {
            float4 g = gp[i];
            d += xv[i].x * g.x + xv[i].y * g.y + xv[i].z * g.z + xv[i].w * g.w;
        }
#pragma unroll
        for (int off = 32; off; off >>= 1) d += __shfl_xor(d, off);
        l[e] = d;   // all lanes now hold the full dot
    }
#pragma unroll
    for (int e = 0; e < E_NUM; e++)
        if (lane == e) logits[(size_t)t * E_NUM + e] = l[e];

    // top-2 (ties: lower index first, matches jax top_k)
    int e0 = 0; float v0 = l[0];
#pragma unroll
    for (int e = 1; e < E_NUM; e++) if (l[e] > v0) { v0 = l[e]; e0 = e; }
    int e1 = 0; float v1 = -3.4e38f;
#pragma unroll
    for (int e = 0; e < E_NUM; e++) if (e != e0 && l[e] > v1) { v1 = l[e]; e1 = e; }
    // normalized top-2 softmax weights (full-softmax denominator cancels)
    const float p1 = __expf(v1 - v0);
    const float w0 = 1.f / (1.f + p1);
    const float w1 = p1 * w0;

#pragma unroll
    for (int k = 0; k < 2; k++) {
        const int   ek = k ? e1 : e0;
        const float wk = k ? w1 : w0;
        int pos = 0;
        if (lane == 0) pos = atomicAdd(&counts[ek], 1);
        pos = __shfl(pos, 0);
        if (lane == 0) tok[ek * T_TOK + pos] = t;
        unsigned short* dst = Xe + ((size_t)ek * T_TOK + pos) * D_DIM + lane * 16;
        uint4 o0, o1;
        o0.x = pack2(xv[0].x * wk, xv[0].y * wk); o0.y = pack2(xv[0].z * wk, xv[0].w * wk);
        o0.z = pack2(xv[1].x * wk, xv[1].y * wk); o0.w = pack2(xv[1].z * wk, xv[1].w * wk);
        o1.x = pack2(xv[2].x * wk, xv[2].y * wk); o1.y = pack2(xv[2].z * wk, xv[2].w * wk);
        o1.z = pack2(xv[3].x * wk, xv[3].y * wk); o1.w = pack2(xv[3].z * wk, xv[3].w * wk);
        ((uint4*)dst)[0] = o0; ((uint4*)dst)[1] = o1;
    }
}

// ---------------------------------------------------------------------------
// GEMM1: C[cnt, 7168] = Xe[cnt,1024] x W13^T, fused SwiGLU -> H bf16 [*, 3584].
// W13 row n: blk=n/32, rem=n%32; rem<16 -> w1[f=blk*16+rem], else w3[f=...].
// So n-tiles pair up (g,u) within the same lane's accumulators.
// ---------------------------------------------------------------------------
__global__ __launch_bounds__(256)
void moe_gemm1(const unsigned short* __restrict__ Xe,
               const float* __restrict__ w1, const float* __restrict__ w3,
               const int* __restrict__ counts, unsigned short* __restrict__ H,
               int e)
{
    const int cnt = counts[e];
    const int m0 = blockIdx.y * BM;
    if (m0 >= cnt) return;
    const int n0 = blockIdx.x * BN;

    const unsigned short* A = Xe + (size_t)e * T_TOK * D_DIM;
    const float* W1 = w1 + (size_t)e * F_DIM * D_DIM;
    const float* W3 = w3 + (size_t)e * F_DIM * D_DIM;

    __shared__ unsigned short As[BM * BK];
    __shared__ unsigned short Bs[BN * BK];

    const int tid = threadIdx.x;
    const int lane = tid & 63, wave = tid >> 6;
    const int wm = (wave >> 1) * 64, wn = (wave & 1) * 64;

    // staging: each thread moves 16 contiguous elements of one tile row
    const int sr = tid >> 1;
    const int sc = (tid & 1) * 16;

    const int am = m0 + sr;
    const bool aok = (am < cnt);
    const unsigned short* arow = A + (size_t)am * D_DIM + sc;

    const int ng = n0 + sr;
    const int blk = ng >> 5, rem = ng & 31;
    const float* brow = (rem < 16)
        ? (W1 + (size_t)(blk * 16 + rem) * D_DIM + sc)
        : (W3 + (size_t)(blk * 16 + rem - 16) * D_DIM + sc);

    f32x4 acc[4][4] = {};

    const int ko = (lane >> 4) * 8;
    const int mr = wm + (lane & 15);
    const int nr = wn + (lane & 15);

    for (int k0 = 0; k0 < D_DIM; k0 += BK) {
        uint4 a0 = {0, 0, 0, 0}, a1 = {0, 0, 0, 0};
        if (aok) {
            a0 = ((const uint4*)(arow + k0))[0];
            a1 = ((const uint4*)(arow + k0))[1];
        }
        const float4* bp = (const float4*)(brow + k0);
        float4 b0 = bp[0], b1 = bp[1], b2 = bp[2], b3 = bp[3];
        uint4 pb0, pb1;
        pb0.x = pack2(b0.x, b0.y); pb0.y = pack2(b0.z, b0.w);
        pb0.z = pack2(b1.x, b1.y); pb0.w = pack2(b1.z, b1.w);
        pb1.x = pack2(b2.x, b2.y); pb1.y = pack2(b2.z, b2.w);
        pb1.z = pack2(b3.x, b3.y); pb1.w = pack2(b3.z, b3.w);

        __syncthreads();
        ((uint4*)&As[sr * BK + sc])[0] = a0;
        ((uint4*)&As[sr * BK + sc])[1] = a1;
        ((uint4*)&Bs[sr * BK + sc])[0] = pb0;
        ((uint4*)&Bs[sr * BK + sc])[1] = pb1;
        __syncthreads();

        bf16x8 af[4], bfm[4];
#pragma unroll
        for (int i = 0; i < 4; i++) {
            af[i]  = *(const bf16x8*)&As[(mr + i * 16) * BK + ko];
            bfm[i] = *(const bf16x8*)&Bs[(nr + i * 16) * BK + ko];
        }
#pragma unroll
        for (int mi = 0; mi < 4; mi++)
#pragma unroll
            for (int ni = 0; ni < 4; ni++)
                acc[mi][ni] = __builtin_amdgcn_mfma_f32_16x16x32_bf16(
                    af[mi], bfm[ni], acc[mi][ni], 0, 0, 0);
    }

    // SwiGLU epilogue: tiles (0,1) and (2,3) are (g,u) pairs in-lane.
    const int fb = ((n0 + wn) >> 1) + (lane & 15);
#pragma unroll
    for (int mi = 0; mi < 4; mi++) {
        const int mrow = m0 + wm + mi * 16 + ((lane >> 4) << 2);
#pragma unroll
        for (int p = 0; p < 2; p++) {
            f32x4 g = acc[mi][2 * p];
            f32x4 u = acc[mi][2 * p + 1];
            const int f = fb + p * 16;
#pragma unroll
            for (int r = 0; r < 4; r++) {
                float gv = g[r];
                float hv = (gv / (1.f + __expf(-gv))) * u[r];
                // rows >= cnt get exact 0 here (A zero-padded) -> GEMM2 safe
                H[(size_t)(mrow + r) * F_DIM + f] = (unsigned short)f2bf_u(hv);
            }
        }
    }
}

// ---------------------------------------------------------------------------
// GEMM2: out[tok[m], :] += H[m, 0:3584] x w2[e]^T  (w2[e] is [D, F] row-major)
// ---------------------------------------------------------------------------
__global__ __launch_bounds__(256)
void moe_gemm2(const unsigned short* __restrict__ H, const float* __restrict__ w2,
               const int* __restrict__ counts, const int* __restrict__ tok,
               float* __restrict__ out, int e)
{
    const int cnt = counts[e];
    const int m0 = blockIdx.y * BM;
    if (m0 >= cnt) return;
    const int n0 = blockIdx.x * BN;

    const float* W2 = w2 + (size_t)e * D_DIM * F_DIM;
    const int* tk = tok + e * T_TOK;

    __shared__ unsigned short As[BM * BK];
    __shared__ unsigned short Bs[BN * BK];

    const int tid = threadIdx.x;
    const int lane = tid & 63, wave = tid >> 6;
    const int wm = (wave >> 1) * 64, wn = (wave & 1) * 64;
    const int sr = tid >> 1, sc = (tid & 1) * 16;

    // H rows m0..m0+127 were all written by GEMM1 (same launch predicate),
    // rows >= cnt are exact zeros -> no A guard needed.
    const unsigned short* arow = H + (size_t)(m0 + sr) * F_DIM + sc;
    const float* brow = W2 + (size_t)(n0 + sr) * F_DIM + sc;

    f32x4 acc[4][4] = {};
    const int ko = (lane >> 4) * 8;
    const int mr = wm + (lane & 15);
    const int nr = wn + (lane & 15);

    for (int k0 = 0; k0 < F_DIM; k0 += BK) {
        uint4 a0 = ((const uint4*)(arow + k0))[0];
        uint4 a1 = ((const uint4*)(arow + k0))[1];
        const float4* bp = (const float4*)(brow + k0);
        float4 b0 = bp[0], b1 = bp[1], b2 = bp[2], b3 = bp[3];
        uint4 pb0, pb1;
        pb0.x = pack2(b0.x, b0.y); pb0.y = pack2(b0.z, b0.w);
        pb0.z = pack2(b1.x, b1.y); pb0.w = pack2(b1.z, b1.w);
        pb1.x = pack2(b2.x, b2.y); pb1.y = pack2(b2.z, b2.w);
        pb1.z = pack2(b3.x, b3.y); pb1.w = pack2(b3.z, b3.w);

        __syncthreads();
        ((uint4*)&As[sr * BK + sc])[0] = a0;
        ((uint4*)&As[sr * BK + sc])[1] = a1;
        ((uint4*)&Bs[sr * BK + sc])[0] = pb0;
        ((uint4*)&Bs[sr * BK + sc])[1] = pb1;
        __syncthreads();

        bf16x8 af[4], bfm[4];
#pragma unroll
        for (int i = 0; i < 4; i++) {
            af[i]  = *(const bf16x8*)&As[(mr + i * 16) * BK + ko];
            bfm[i] = *(const bf16x8*)&Bs[(nr + i * 16) * BK + ko];
        }
#pragma unroll
        for (int mi = 0; mi < 4; mi++)
#pragma unroll
            for (int ni = 0; ni < 4; ni++)
                acc[mi][ni] = __builtin_amdgcn_mfma_f32_16x16x32_bf16(
                    af[mi], bfm[ni], acc[mi][ni], 0, 0, 0);
    }

    // scatter-add epilogue; guard m < cnt (token list beyond cnt is poison)
#pragma unroll
    for (int mi = 0; mi < 4; mi++) {
        const int mbase = m0 + wm + mi * 16 + ((lane >> 4) << 2);
#pragma unroll
        for (int r = 0; r < 4; r++) {
            const int m = mbase + r;
            if (m < cnt) {
                const int t = tk[m];
                float* orow = out + (size_t)t * D_DIM + n0 + wn + (lane & 15);
#pragma unroll
                for (int ni = 0; ni < 4; ni++)
                    atomicAdd(orow + ni * 16, acc[mi][ni][r]);
            }
        }
    }
}

// ---------------------------------------------------------------------------
extern "C" void kernel_launch(void* const* d_in, const int* in_sizes, int n_in,
                              void* d_out, int out_size, void* d_ws, size_t ws_size,
                              hipStream_t stream)
{
    const float* x  = (const float*)d_in[0];   // [T, D]
    const float* gw = (const float*)d_in[1];   // [E, D]
    const float* w1 = (const float*)d_in[2];   // [E, F, D]
    const float* w3 = (const float*)d_in[3];   // [E, F, D]
    const float* w2 = (const float*)d_in[4];   // [E, D, F]
    float* out    = (float*)d_out;                       // [T, D]
    float* logits = out + (size_t)T_TOK * D_DIM;         // [T, E]

    // workspace layout (~96.6 MB)
    char* ws = (char*)d_ws;
    int* counts = (int*)ws;                                              // 32 B (pad 256)
    int* tok    = (int*)(ws + 256);                                      // 128 KB
    unsigned short* Xe = (unsigned short*)(ws + 256 + E_NUM * T_TOK * 4); // 64 MB
    unsigned short* H  = Xe + (size_t)E_NUM * T_TOK * D_DIM;              // 28.7 MB

    hipMemsetAsync(out, 0, (size_t)T_TOK * D_DIM * sizeof(float), stream);
    hipMemsetAsync(counts, 0, E_NUM * sizeof(int), stream);

    router_gather<<<T_TOK / 4, 256, 0, stream>>>(x, gw, logits, counts, tok, Xe);

    for (int e = 0; e < E_NUM; e++) {
        moe_gemm1<<<dim3(N13 / BN, T_TOK / BM), 256, 0, stream>>>(Xe, w1, w3, counts, H, e);
        moe_gemm2<<<dim3(D_DIM / BN, T_TOK / BM), 256, 0, stream>>>(H, w2, counts, tok, out, e);
    }
}

// Round 2
// 833.782 us; speedup vs baseline: 2.2983x; 2.2983x over previous
//
#include <hip/hip_runtime.h>

// MoE top-2 of 8 experts. T=4096 tokens, D=1024, F=3584.
// router -> gather(compact bf16 rows) -> GEMM1 all-experts (SwiGLU fused)
//        -> GEMM2 all-experts (atomic scatter).
// GEMMs: bf16 MFMA 16x16x32, 128x128x32 tiles, 4 waves of 4x4 acc tiles.
// Experts fused into one launch via gridDim.z (R1 lesson: per-expert
// launches gave 64 active blocks -> 3% occupancy, 160us each).

#define T_TOK 4096
#define D_DIM 1024
#define F_DIM 3584
#define E_NUM 8
#define N13   (2 * F_DIM)   // 7168: w1/w3 interleaved in 16-row blocks
#define BM 128
#define BN 128
#define BK 32
#define LDK (BK + 8)        // +8 shorts: ds_read_b128 2-way bank aliasing (free)
#define MAXROWS (2 * T_TOK + E_NUM * (BM - 1) + 8)  // compacted row bound

typedef __bf16 bf16x8 __attribute__((ext_vector_type(8)));
typedef float  f32x4  __attribute__((ext_vector_type(4)));

__device__ __forceinline__ unsigned f2bf_u(float f) {
    unsigned u = __builtin_bit_cast(unsigned, f);
    return (u + 0x7FFFu + ((u >> 16) & 1u)) >> 16;   // RNE
}
__device__ __forceinline__ unsigned pack2(float lo, float hi) {
    return f2bf_u(lo) | (f2bf_u(hi) << 16);
}
// exclusive scan of counts rounded up to BM, computed inline (8 cached loads)
__device__ __forceinline__ int expert_off(const int* __restrict__ counts, int e) {
    int off = 0;
    for (int i = 0; i < e; i++) off += (counts[i] + BM - 1) & ~(BM - 1);
    return off;
}

// ---------------------------------------------------------------------------
// Router: 1 wave per token. fp32 logits, top-2, counts/tok/wgt lists.
// ---------------------------------------------------------------------------
__global__ __launch_bounds__(256)
void router(const float* __restrict__ x, const float* __restrict__ gw,
            float* __restrict__ logits, int* __restrict__ counts,
            int* __restrict__ tok, float* __restrict__ wgt)
{
    const int wave = threadIdx.x >> 6;
    const int lane = threadIdx.x & 63;
    const int t = blockIdx.x * 4 + wave;

    const float* xt = x + (size_t)t * D_DIM + lane * 16;
    float4 xv[4];
#pragma unroll
    for (int i = 0; i < 4; i++) xv[i] = ((const float4*)xt)[i];

    float l[E_NUM];
#pragma unroll
    for (int e = 0; e < E_NUM; e++) {
        const float4* gp = (const float4*)(gw + (size_t)e * D_DIM + lane * 16);
        float d = 0.f;
#pragma unroll
        for (int i = 0; i < 4; i++) {
            float4 g = gp[i];
            d += xv[i].x * g.x + xv[i].y * g.y + xv[i].z * g.z + xv[i].w * g.w;
        }
#pragma unroll
        for (int off = 32; off; off >>= 1) d += __shfl_xor(d, off);
        l[e] = d;
    }
#pragma unroll
    for (int e = 0; e < E_NUM; e++)
        if (lane == e) logits[(size_t)t * E_NUM + e] = l[e];

    int e0 = 0; float v0 = l[0];
#pragma unroll
    for (int e = 1; e < E_NUM; e++) if (l[e] > v0) { v0 = l[e]; e0 = e; }
    int e1 = 0; float v1 = -3.4e38f;
#pragma unroll
    for (int e = 0; e < E_NUM; e++) if (e != e0 && l[e] > v1) { v1 = l[e]; e1 = e; }
    const float p1 = __expf(v1 - v0);
    const float w0 = 1.f / (1.f + p1);
    const float w1 = p1 * w0;

    if (lane < 2) {
        const int   ek = lane ? e1 : e0;
        const float wk = lane ? w1 : w0;
        const int pos = atomicAdd(&counts[ek], 1);
        tok[ek * T_TOK + pos] = t;
        wgt[ek * T_TOK + pos] = wk;
    }
}

// ---------------------------------------------------------------------------
// Gather: build compacted bf16 rows Xe[moff[e]+r] = x[tok[r]] * wgt[r],
// zero rows for r in [cnt, cntpad). Block = (expert, row-tile of 128).
// ---------------------------------------------------------------------------
__global__ __launch_bounds__(256)
void gather(const float* __restrict__ x, const int* __restrict__ counts,
            const int* __restrict__ tok, const float* __restrict__ wgt,
            unsigned short* __restrict__ Xe)
{
    const int e = blockIdx.y;
    const int cnt = counts[e];
    const int cntpad = (cnt + BM - 1) & ~(BM - 1);
    const int r0 = blockIdx.x * BM;
    if (r0 >= cntpad) return;
    const int moff = expert_off(counts, e);

    const int tid = threadIdx.x;
    const int chunk = tid & 63;          // 64 chunks of 16 elems per row
    const int rsub = tid >> 6;           // 4 rows in flight
#pragma unroll
    for (int i = 0; i < 32; i++) {
        const int r = r0 + rsub + i * 4;
        unsigned short* dst = Xe + (size_t)(moff + r) * D_DIM + chunk * 16;
        uint4 o0 = {0,0,0,0}, o1 = {0,0,0,0};
        if (r < cnt) {
            const int t = tok[e * T_TOK + r];
            const float w = wgt[e * T_TOK + r];
            const float4* src = (const float4*)(x + (size_t)t * D_DIM + chunk * 16);
            float4 a = src[0], b = src[1], c = src[2], d = src[3];
            o0.x = pack2(a.x*w, a.y*w); o0.y = pack2(a.z*w, a.w*w);
            o0.z = pack2(b.x*w, b.y*w); o0.w = pack2(b.z*w, b.w*w);
            o1.x = pack2(c.x*w, c.y*w); o1.y = pack2(c.z*w, c.w*w);
            o1.z = pack2(d.x*w, d.y*w); o1.w = pack2(d.z*w, d.w*w);
        }
        ((uint4*)dst)[0] = o0; ((uint4*)dst)[1] = o1;
    }
}

// ---------------------------------------------------------------------------
// GEMM1: H[row, 3584] = SwiGLU(Xe[row,1024] x W13^T). grid.z = expert.
// ---------------------------------------------------------------------------
__global__ __launch_bounds__(256)
void moe_gemm1(const unsigned short* __restrict__ Xe,
               const float* __restrict__ w1, const float* __restrict__ w3,
               const int* __restrict__ counts, unsigned short* __restrict__ H)
{
    const int e = blockIdx.z;
    const int cnt = counts[e];
    const int m0 = blockIdx.y * BM;
    if (m0 >= cnt) return;
    const int moff = expert_off(counts, e);
    const int n0 = blockIdx.x * BN;

    const float* W1 = w1 + (size_t)e * F_DIM * D_DIM;
    const float* W3 = w3 + (size_t)e * F_DIM * D_DIM;

    __shared__ unsigned short As[BM * LDK];
    __shared__ unsigned short Bs[BN * LDK];

    const int tid = threadIdx.x;
    const int lane = tid & 63, wave = tid >> 6;
    const int wm = (wave >> 1) * 64, wn = (wave & 1) * 64;
    const int sr = tid >> 1, sc = (tid & 1) * 16;

    // compacted rows are always valid (zero-padded) -> no A guard
    const unsigned short* arow = Xe + (size_t)(moff + m0 + sr) * D_DIM + sc;

    const int ng = n0 + sr;
    const int blk = ng >> 5, rem = ng & 31;
    const float* brow = (rem < 16)
        ? (W1 + (size_t)(blk * 16 + rem) * D_DIM + sc)
        : (W3 + (size_t)(blk * 16 + rem - 16) * D_DIM + sc);

    f32x4 acc[4][4] = {};
    const int ko = (lane >> 4) * 8;
    const int mr = wm + (lane & 15);
    const int nr = wn + (lane & 15);

    for (int k0 = 0; k0 < D_DIM; k0 += BK) {
        uint4 a0 = ((const uint4*)(arow + k0))[0];
        uint4 a1 = ((const uint4*)(arow + k0))[1];
        const float4* bp = (const float4*)(brow + k0);
        float4 b0 = bp[0], b1 = bp[1], b2 = bp[2], b3 = bp[3];
        uint4 pb0, pb1;
        pb0.x = pack2(b0.x, b0.y); pb0.y = pack2(b0.z, b0.w);
        pb0.z = pack2(b1.x, b1.y); pb0.w = pack2(b1.z, b1.w);
        pb1.x = pack2(b2.x, b2.y); pb1.y = pack2(b2.z, b2.w);
        pb1.z = pack2(b3.x, b3.y); pb1.w = pack2(b3.z, b3.w);

        __syncthreads();
        ((uint4*)&As[sr * LDK + sc])[0] = a0;
        ((uint4*)&As[sr * LDK + sc])[1] = a1;
        ((uint4*)&Bs[sr * LDK + sc])[0] = pb0;
        ((uint4*)&Bs[sr * LDK + sc])[1] = pb1;
        __syncthreads();

        bf16x8 af[4], bfm[4];
#pragma unroll
        for (int i = 0; i < 4; i++) {
            af[i]  = *(const bf16x8*)&As[(mr + i * 16) * LDK + ko];
            bfm[i] = *(const bf16x8*)&Bs[(nr + i * 16) * LDK + ko];
        }
#pragma unroll
        for (int mi = 0; mi < 4; mi++)
#pragma unroll
            for (int ni = 0; ni < 4; ni++)
                acc[mi][ni] = __builtin_amdgcn_mfma_f32_16x16x32_bf16(
                    af[mi], bfm[ni], acc[mi][ni], 0, 0, 0);
    }

    // SwiGLU epilogue: tiles (0,1),(2,3) are (g,u) pairs in-lane
    const int fb = ((n0 + wn) >> 1) + (lane & 15);
#pragma unroll
    for (int mi = 0; mi < 4; mi++) {
        const int mrow = moff + m0 + wm + mi * 16 + ((lane >> 4) << 2);
#pragma unroll
        for (int p = 0; p < 2; p++) {
            f32x4 g = acc[mi][2 * p];
            f32x4 u = acc[mi][2 * p + 1];
            const int f = fb + p * 16;
#pragma unroll
            for (int r = 0; r < 4; r++) {
                float gv = g[r];
                float hv = (gv / (1.f + __expf(-gv))) * u[r];
                H[(size_t)(mrow + r) * F_DIM + f] = (unsigned short)f2bf_u(hv);
            }
        }
    }
}

// ---------------------------------------------------------------------------
// GEMM2: out[tok[m], :] += H[row] x w2[e]^T. grid.z = expert.
// ---------------------------------------------------------------------------
__global__ __launch_bounds__(256)
void moe_gemm2(const unsigned short* __restrict__ H, const float* __restrict__ w2,
               const int* __restrict__ counts, const int* __restrict__ tok,
               float* __restrict__ out)
{
    const int e = blockIdx.z;
    const int cnt = counts[e];
    const int m0 = blockIdx.y * BM;
    if (m0 >= cnt) return;
    const int moff = expert_off(counts, e);
    const int n0 = blockIdx.x * BN;

    const float* W2 = w2 + (size_t)e * D_DIM * F_DIM;
    const int* tk = tok + e * T_TOK;

    __shared__ unsigned short As[BM * LDK];
    __shared__ unsigned short Bs[BN * LDK];

    const int tid = threadIdx.x;
    const int lane = tid & 63, wave = tid >> 6;
    const int wm = (wave >> 1) * 64, wn = (wave & 1) * 64;
    const int sr = tid >> 1, sc = (tid & 1) * 16;

    const unsigned short* arow = H + (size_t)(moff + m0 + sr) * F_DIM + sc;
    const float* brow = W2 + (size_t)(n0 + sr) * F_DIM + sc;

    f32x4 acc[4][4] = {};
    const int ko = (lane >> 4) * 8;
    const int mr = wm + (lane & 15);
    const int nr = wn + (lane & 15);

    for (int k0 = 0; k0 < F_DIM; k0 += BK) {
        uint4 a0 = ((const uint4*)(arow + k0))[0];
        uint4 a1 = ((const uint4*)(arow + k0))[1];
        const float4* bp = (const float4*)(brow + k0);
        float4 b0 = bp[0], b1 = bp[1], b2 = bp[2], b3 = bp[3];
        uint4 pb0, pb1;
        pb0.x = pack2(b0.x, b0.y); pb0.y = pack2(b0.z, b0.w);
        pb0.z = pack2(b1.x, b1.y); pb0.w = pack2(b1.z, b1.w);
        pb1.x = pack2(b2.x, b2.y); pb1.y = pack2(b2.z, b2.w);
        pb1.z = pack2(b3.x, b3.y); pb1.w = pack2(b3.z, b3.w);

        __syncthreads();
        ((uint4*)&As[sr * LDK + sc])[0] = a0;
        ((uint4*)&As[sr * LDK + sc])[1] = a1;
        ((uint4*)&Bs[sr * LDK + sc])[0] = pb0;
        ((uint4*)&Bs[sr * LDK + sc])[1] = pb1;
        __syncthreads();

        bf16x8 af[4], bfm[4];
#pragma unroll
        for (int i = 0; i < 4; i++) {
            af[i]  = *(const bf16x8*)&As[(mr + i * 16) * LDK + ko];
            bfm[i] = *(const bf16x8*)&Bs[(nr + i * 16) * LDK + ko];
        }
#pragma unroll
        for (int mi = 0; mi < 4; mi++)
#pragma unroll
            for (int ni = 0; ni < 4; ni++)
                acc[mi][ni] = __builtin_amdgcn_mfma_f32_16x16x32_bf16(
                    af[mi], bfm[ni], acc[mi][ni], 0, 0, 0);
    }

#pragma unroll
    for (int mi = 0; mi < 4; mi++) {
        const int mbase = m0 + wm + mi * 16 + ((lane >> 4) << 2);
#pragma unroll
        for (int r = 0; r < 4; r++) {
            const int m = mbase + r;
            if (m < cnt) {
                const int t = tk[m];
                float* orow = out + (size_t)t * D_DIM + n0 + wn + (lane & 15);
#pragma unroll
                for (int ni = 0; ni < 4; ni++)
                    atomicAdd(orow + ni * 16, acc[mi][ni][r]);
            }
        }
    }
}

// ---------------------------------------------------------------------------
extern "C" void kernel_launch(void* const* d_in, const int* in_sizes, int n_in,
                              void* d_out, int out_size, void* d_ws, size_t ws_size,
                              hipStream_t stream)
{
    const float* x  = (const float*)d_in[0];   // [T, D]
    const float* gw = (const float*)d_in[1];   // [E, D]
    const float* w1 = (const float*)d_in[2];   // [E, F, D]
    const float* w3 = (const float*)d_in[3];   // [E, F, D]
    const float* w2 = (const float*)d_in[4];   // [E, D, F]
    float* out    = (float*)d_out;                       // [T, D]
    float* logits = out + (size_t)T_TOK * D_DIM;         // [T, E]

    // workspace layout (~85 MB)
    char* ws = (char*)d_ws;
    int*   counts = (int*)ws;                                       // pad 256B
    int*   tok    = (int*)(ws + 256);                               // 128 KB
    float* wgt    = (float*)(ws + 256 + E_NUM * T_TOK * 4);         // 128 KB
    unsigned short* Xe = (unsigned short*)(ws + 256 + 2 * E_NUM * T_TOK * 4); // 18.9 MB
    unsigned short* H  = Xe + (size_t)MAXROWS * D_DIM;                         // 66 MB

    hipMemsetAsync(out, 0, (size_t)T_TOK * D_DIM * sizeof(float), stream);
    hipMemsetAsync(counts, 0, E_NUM * sizeof(int), stream);

    router<<<T_TOK / 4, 256, 0, stream>>>(x, gw, logits, counts, tok, wgt);
    gather<<<dim3(T_TOK / BM, E_NUM), 256, 0, stream>>>(x, counts, tok, wgt, Xe);
    moe_gemm1<<<dim3(N13 / BN, T_TOK / BM, E_NUM), 256, 0, stream>>>(Xe, w1, w3, counts, H);
    moe_gemm2<<<dim3(D_DIM / BN, T_TOK / BM, E_NUM), 256, 0, stream>>>(H, w2, counts, tok, out);
}

// Round 3
// 770.152 us; speedup vs baseline: 2.4882x; 1.0826x over previous
//
#include <hip/hip_runtime.h>

// MoE top-2 of 8 experts. T=4096, D=1024, F=3584.
// Full path (ws >= ~295MB): preconvert weights to bf16, m97-style GEMMs with
// global_load_lds staging, slot-indexed non-atomic GEMM2 output + combine.
// Fallback path (ws >= ~85MB): round-2 inline-convert kernels.

#define T_TOK 4096
#define D_DIM 1024
#define F_DIM 3584
#define E_NUM 8
#define N13   (2 * F_DIM)   // 7168: w1/w3 interleaved in 16-row blocks
#define BM 128
#define BN 128
#define BK 32
#define LDK (BK + 8)        // legacy kernels only
#define MAXROWS 9216        // sum of per-expert 128-padded counts <= 8192+8*127

typedef __bf16 bf16x8 __attribute__((ext_vector_type(8)));
typedef float  f32x4  __attribute__((ext_vector_type(4)));

__device__ __forceinline__ unsigned f2bf_u(float f) {
    unsigned u = __builtin_bit_cast(unsigned, f);
    return (u + 0x7FFFu + ((u >> 16) & 1u)) >> 16;   // RNE
}
__device__ __forceinline__ unsigned pack2(float lo, float hi) {
    return f2bf_u(lo) | (f2bf_u(hi) << 16);
}
__device__ __forceinline__ int expert_off(const int* __restrict__ counts, int e) {
    int off = 0;
    for (int i = 0; i < e; i++) off += (counts[i] + BM - 1) & ~(BM - 1);
    return off;
}
// async global->LDS, 16B per lane; LDS dest = uniform base + lane*16
__device__ __forceinline__ void load_lds16(const void* g, void* l) {
    __builtin_amdgcn_global_load_lds(
        (const __attribute__((address_space(1))) unsigned*)g,
        (__attribute__((address_space(3))) unsigned*)l, 16, 0, 0);
}

// ---------------------------------------------------------------------------
// Router: 1 wave/token. logits fp32; tok entry = (t<<1)|slot.
// ---------------------------------------------------------------------------
__global__ __launch_bounds__(256)
void router(const float* __restrict__ x, const float* __restrict__ gw,
            float* __restrict__ logits, int* __restrict__ counts,
            int* __restrict__ tok, float* __restrict__ wgt)
{
    const int wave = threadIdx.x >> 6;
    const int lane = threadIdx.x & 63;
    const int t = blockIdx.x * 4 + wave;

    const float* xt = x + (size_t)t * D_DIM + lane * 16;
    float4 xv[4];
#pragma unroll
    for (int i = 0; i < 4; i++) xv[i] = ((const float4*)xt)[i];

    float l[E_NUM];
#pragma unroll
    for (int e = 0; e < E_NUM; e++) {
        const float4* gp = (const float4*)(gw + (size_t)e * D_DIM + lane * 16);
        float d = 0.f;
#pragma unroll
        for (int i = 0; i < 4; i++) {
            float4 g = gp[i];
            d += xv[i].x * g.x + xv[i].y * g.y + xv[i].z * g.z + xv[i].w * g.w;
        }
#pragma unroll
        for (int off = 32; off; off >>= 1) d += __shfl_xor(d, off);
        l[e] = d;
    }
#pragma unroll
    for (int e = 0; e < E_NUM; e++)
        if (lane == e) logits[(size_t)t * E_NUM + e] = l[e];

    int e0 = 0; float v0 = l[0];
#pragma unroll
    for (int e = 1; e < E_NUM; e++) if (l[e] > v0) { v0 = l[e]; e0 = e; }
    int e1 = 0; float v1 = -3.4e38f;
#pragma unroll
    for (int e = 0; e < E_NUM; e++) if (e != e0 && l[e] > v1) { v1 = l[e]; e1 = e; }
    const float p1 = __expf(v1 - v0);
    const float w0 = 1.f / (1.f + p1);
    const float w1 = p1 * w0;

    if (lane < 2) {
        const int   ek = lane ? e1 : e0;
        const float wk = lane ? w1 : w0;
        const int pos = atomicAdd(&counts[ek], 1);
        tok[ek * T_TOK + pos] = (t << 1) | lane;
        wgt[ek * T_TOK + pos] = wk;
    }
}

// ---------------------------------------------------------------------------
// Gather: compacted bf16 rows Xe = x[t]*w, zero padding to 128-multiples.
// ---------------------------------------------------------------------------
__global__ __launch_bounds__(256)
void gather(const float* __restrict__ x, const int* __restrict__ counts,
            const int* __restrict__ tok, const float* __restrict__ wgt,
            unsigned short* __restrict__ Xe)
{
    const int e = blockIdx.y;
    const int cnt = counts[e];
    const int cntpad = (cnt + BM - 1) & ~(BM - 1);
    const int r0 = blockIdx.x * BM;
    if (r0 >= cntpad) return;
    const int moff = expert_off(counts, e);

    const int tid = threadIdx.x;
    const int chunk = tid & 63;
    const int rsub = tid >> 6;
#pragma unroll
    for (int i = 0; i < 32; i++) {
        const int r = r0 + rsub + i * 4;
        unsigned short* dst = Xe + (size_t)(moff + r) * D_DIM + chunk * 16;
        uint4 o0 = {0,0,0,0}, o1 = {0,0,0,0};
        if (r < cnt) {
            const int t = tok[e * T_TOK + r] >> 1;
            const float w = wgt[e * T_TOK + r];
            const float4* src = (const float4*)(x + (size_t)t * D_DIM + chunk * 16);
            float4 a = src[0], b = src[1], c = src[2], d = src[3];
            o0.x = pack2(a.x*w, a.y*w); o0.y = pack2(a.z*w, a.w*w);
            o0.z = pack2(b.x*w, b.y*w); o0.w = pack2(b.z*w, b.w*w);
            o1.x = pack2(c.x*w, c.y*w); o1.y = pack2(c.z*w, c.w*w);
            o1.z = pack2(d.x*w, d.y*w); o1.w = pack2(d.z*w, d.w*w);
        }
        ((uint4*)dst)[0] = o0; ((uint4*)dst)[1] = o1;
    }
}

// ---------------------------------------------------------------------------
// Weight preconversion (memory-bound; VALU is free here).
// W13bf row ng of expert e: blk=ng/32, rem=ng%32 -> w1/w3[f=blk*16+(rem&15)].
// ---------------------------------------------------------------------------
__global__ __launch_bounds__(256)
void conv_w13(const float* __restrict__ w1, const float* __restrict__ w3,
              unsigned short* __restrict__ W13)
{
    const size_t idx = (size_t)blockIdx.x * 256 + threadIdx.x;  // 8-elem chunk
    const size_t c = idx * 8;
    const int col = (int)(c & (D_DIM - 1));
    const int r   = (int)(c >> 10);          // global row in [0, E*N13)
    const int e   = r / N13;
    const int ng  = r - e * N13;
    const int blk = ng >> 5, rem = ng & 31;
    const float* src = ((rem < 16) ? w1 : w3)
        + ((size_t)e * F_DIM + blk * 16 + (rem & 15)) * D_DIM + col;
    float4 a = ((const float4*)src)[0], b = ((const float4*)src)[1];
    uint4 o;
    o.x = pack2(a.x, a.y); o.y = pack2(a.z, a.w);
    o.z = pack2(b.x, b.y); o.w = pack2(b.z, b.w);
    *(uint4*)(W13 + c) = o;
}

__global__ __launch_bounds__(256)
void conv_w2(const float* __restrict__ w2, unsigned short* __restrict__ W2)
{
    const size_t idx = (size_t)blockIdx.x * 256 + threadIdx.x;
    const size_t c = idx * 8;
    float4 a = ((const float4*)(w2 + c))[0], b = ((const float4*)(w2 + c))[1];
    uint4 o;
    o.x = pack2(a.x, a.y); o.y = pack2(a.z, a.w);
    o.z = pack2(b.x, b.y); o.w = pack2(b.z, b.w);
    *(uint4*)(W2 + c) = o;
}

// ---------------------------------------------------------------------------
// GEMM1 (bf16 weights): H = SwiGLU(Xe x W13^T). m97-style staging.
// ---------------------------------------------------------------------------
__global__ __launch_bounds__(256)
void gemm1_bf(const unsigned short* __restrict__ Xe,
              const unsigned short* __restrict__ W13,
              const int* __restrict__ counts, unsigned short* __restrict__ H)
{
    const int e = blockIdx.z;
    const int cnt = counts[e];
    const int m0 = blockIdx.y * BM;
    if (m0 >= cnt) return;
    const int moff = expert_off(counts, e);
    const int n0 = blockIdx.x * BN;

    __shared__ unsigned short As[BM * BK];
    __shared__ unsigned short Bs[BN * BK];

    const int tid = threadIdx.x, lane = tid & 63, wave = tid >> 6;
    const int wm = (wave >> 1) * 64, wn = (wave & 1) * 64;

    // wave w stages rows [w*16, w*16+16) and [64+w*16, ...): lane -> (row, 16B chunk)
    const int lrow = lane >> 2, lch = (lane & 3) * 8;
    const unsigned short* gA0 = Xe + (size_t)(moff + m0 + wave * 16 + lrow) * D_DIM + lch;
    const unsigned short* gA1 = gA0 + (size_t)64 * D_DIM;
    const unsigned short* gB0 = W13 + ((size_t)e * N13 + n0 + wave * 16 + lrow) * D_DIM + lch;
    const unsigned short* gB1 = gB0 + (size_t)64 * D_DIM;
    unsigned short* lA0 = &As[(wave * 16) * BK];
    unsigned short* lA1 = &As[(64 + wave * 16) * BK];
    unsigned short* lB0 = &Bs[(wave * 16) * BK];
    unsigned short* lB1 = &Bs[(64 + wave * 16) * BK];

    f32x4 acc[4][4] = {};
    const int ko = (lane >> 4) * 8;
    const int mr = wm + (lane & 15), nr = wn + (lane & 15);

    for (int k0 = 0; k0 < D_DIM; k0 += BK) {
        load_lds16(gA0, lA0); load_lds16(gA1, lA1);
        load_lds16(gB0, lB0); load_lds16(gB1, lB1);
        gA0 += BK; gA1 += BK; gB0 += BK; gB1 += BK;
        __syncthreads();   // compiler drains vmcnt before barrier

        bf16x8 af[4], bfm[4];
#pragma unroll
        for (int i = 0; i < 4; i++) {
            af[i]  = *(const bf16x8*)&As[(mr + i * 16) * BK + ko];
            bfm[i] = *(const bf16x8*)&Bs[(nr + i * 16) * BK + ko];
        }
#pragma unroll
        for (int mi = 0; mi < 4; mi++)
#pragma unroll
            for (int ni = 0; ni < 4; ni++)
                acc[mi][ni] = __builtin_amdgcn_mfma_f32_16x16x32_bf16(
                    af[mi], bfm[ni], acc[mi][ni], 0, 0, 0);
        __syncthreads();
    }

    const int fb = ((n0 + wn) >> 1) + (lane & 15);
#pragma unroll
    for (int mi = 0; mi < 4; mi++) {
        const int mrow = moff + m0 + wm + mi * 16 + ((lane >> 4) << 2);
#pragma unroll
        for (int p = 0; p < 2; p++) {
            f32x4 g = acc[mi][2 * p];
            f32x4 u = acc[mi][2 * p + 1];
            const int f = fb + p * 16;
#pragma unroll
            for (int r = 0; r < 4; r++) {
                float gv = g[r];
                float hv = (gv / (1.f + __expf(-gv))) * u[r];
                H[(size_t)(mrow + r) * F_DIM + f] = (unsigned short)f2bf_u(hv);
            }
        }
    }
}

// ---------------------------------------------------------------------------
// GEMM2 (bf16 weights): buf[slot][t] = H x W2^T row. Non-atomic slot writes.
// ---------------------------------------------------------------------------
__global__ __launch_bounds__(256)
void gemm2_bf(const unsigned short* __restrict__ H,
              const unsigned short* __restrict__ W2,
              const int* __restrict__ counts, const int* __restrict__ tok,
              float* __restrict__ buf)
{
    const int e = blockIdx.z;
    const int cnt = counts[e];
    const int m0 = blockIdx.y * BM;
    if (m0 >= cnt) return;
    const int moff = expert_off(counts, e);
    const int n0 = blockIdx.x * BN;
    const int* tk = tok + e * T_TOK;

    __shared__ unsigned short As[BM * BK];
    __shared__ unsigned short Bs[BN * BK];

    const int tid = threadIdx.x, lane = tid & 63, wave = tid >> 6;
    const int wm = (wave >> 1) * 64, wn = (wave & 1) * 64;

    const int lrow = lane >> 2, lch = (lane & 3) * 8;
    const unsigned short* gA0 = H + (size_t)(moff + m0 + wave * 16 + lrow) * F_DIM + lch;
    const unsigned short* gA1 = gA0 + (size_t)64 * F_DIM;
    const unsigned short* gB0 = W2 + ((size_t)e * D_DIM + n0 + wave * 16 + lrow) * F_DIM + lch;
    const unsigned short* gB1 = gB0 + (size_t)64 * F_DIM;
    unsigned short* lA0 = &As[(wave * 16) * BK];
    unsigned short* lA1 = &As[(64 + wave * 16) * BK];
    unsigned short* lB0 = &Bs[(wave * 16) * BK];
    unsigned short* lB1 = &Bs[(64 + wave * 16) * BK];

    f32x4 acc[4][4] = {};
    const int ko = (lane >> 4) * 8;
    const int mr = wm + (lane & 15), nr = wn + (lane & 15);

    for (int k0 = 0; k0 < F_DIM; k0 += BK) {
        load_lds16(gA0, lA0); load_lds16(gA1, lA1);
        load_lds16(gB0, lB0); load_lds16(gB1, lB1);
        gA0 += BK; gA1 += BK; gB0 += BK; gB1 += BK;
        __syncthreads();

        bf16x8 af[4], bfm[4];
#pragma unroll
        for (int i = 0; i < 4; i++) {
            af[i]  = *(const bf16x8*)&As[(mr + i * 16) * BK + ko];
            bfm[i] = *(const bf16x8*)&Bs[(nr + i * 16) * BK + ko];
        }
#pragma unroll
        for (int mi = 0; mi < 4; mi++)
#pragma unroll
            for (int ni = 0; ni < 4; ni++)
                acc[mi][ni] = __builtin_amdgcn_mfma_f32_16x16x32_bf16(
                    af[mi], bfm[ni], acc[mi][ni], 0, 0, 0);
        __syncthreads();
    }

#pragma unroll
    for (int mi = 0; mi < 4; mi++) {
        const int mbase = m0 + wm + mi * 16 + ((lane >> 4) << 2);
#pragma unroll
        for (int r = 0; r < 4; r++) {
            const int m = mbase + r;
            if (m < cnt) {
                const int v = tk[m];
                float* orow = buf + ((size_t)(v & 1) * T_TOK + (v >> 1)) * D_DIM
                            + n0 + wn + (lane & 15);
#pragma unroll
                for (int ni = 0; ni < 4; ni++)
                    orow[ni * 16] = acc[mi][ni][r];
            }
        }
    }
}

__global__ __launch_bounds__(256)
void combine(const float* __restrict__ buf, float* __restrict__ out)
{
    const size_t i = (size_t)blockIdx.x * 256 + threadIdx.x;
    float4 a = ((const float4*)buf)[i];
    float4 b = ((const float4*)(buf + (size_t)T_TOK * D_DIM))[i];
    float4 o = {a.x + b.x, a.y + b.y, a.z + b.z, a.w + b.w};
    ((float4*)out)[i] = o;
}

// ===========================================================================
// Legacy fallback (round-2 kernels, inline fp32->bf16 convert, ~85MB ws)
// ===========================================================================
__global__ __launch_bounds__(256)
void legacy_gemm1(const unsigned short* __restrict__ Xe,
                  const float* __restrict__ w1, const float* __restrict__ w3,
                  const int* __restrict__ counts, unsigned short* __restrict__ H)
{
    const int e = blockIdx.z;
    const int cnt = counts[e];
    const int m0 = blockIdx.y * BM;
    if (m0 >= cnt) return;
    const int moff = expert_off(counts, e);
    const int n0 = blockIdx.x * BN;

    const float* W1 = w1 + (size_t)e * F_DIM * D_DIM;
    const float* W3 = w3 + (size_t)e * F_DIM * D_DIM;

    __shared__ unsigned short As[BM * LDK];
    __shared__ unsigned short Bs[BN * LDK];

    const int tid = threadIdx.x;
    const int lane = tid & 63, wave = tid >> 6;
    const int wm = (wave >> 1) * 64, wn = (wave & 1) * 64;
    const int sr = tid >> 1, sc = (tid & 1) * 16;

    const unsigned short* arow = Xe + (size_t)(moff + m0 + sr) * D_DIM + sc;
    const int ng = n0 + sr;
    const int blk = ng >> 5, rem = ng & 31;
    const float* brow = (rem < 16)
        ? (W1 + (size_t)(blk * 16 + rem) * D_DIM + sc)
        : (W3 + (size_t)(blk * 16 + rem - 16) * D_DIM + sc);

    f32x4 acc[4][4] = {};
    const int ko = (lane >> 4) * 8;
    const int mr = wm + (lane & 15);
    const int nr = wn + (lane & 15);

    for (int k0 = 0; k0 < D_DIM; k0 += BK) {
        uint4 a0 = ((const uint4*)(arow + k0))[0];
        uint4 a1 = ((const uint4*)(arow + k0))[1];
        const float4* bp = (const float4*)(brow + k0);
        float4 b0 = bp[0], b1 = bp[1], b2 = bp[2], b3 = bp[3];
        uint4 pb0, pb1;
        pb0.x = pack2(b0.x, b0.y); pb0.y = pack2(b0.z, b0.w);
        pb0.z = pack2(b1.x, b1.y); pb0.w = pack2(b1.z, b1.w);
        pb1.x = pack2(b2.x, b2.y); pb1.y = pack2(b2.z, b2.w);
        pb1.z = pack2(b3.x, b3.y); pb1.w = pack2(b3.z, b3.w);

        __syncthreads();
        ((uint4*)&As[sr * LDK + sc])[0] = a0;
        ((uint4*)&As[sr * LDK + sc])[1] = a1;
        ((uint4*)&Bs[sr * LDK + sc])[0] = pb0;
        ((uint4*)&Bs[sr * LDK + sc])[1] = pb1;
        __syncthreads();

        bf16x8 af[4], bfm[4];
#pragma unroll
        for (int i = 0; i < 4; i++) {
            af[i]  = *(const bf16x8*)&As[(mr + i * 16) * LDK + ko];
            bfm[i] = *(const bf16x8*)&Bs[(nr + i * 16) * LDK + ko];
        }
#pragma unroll
        for (int mi = 0; mi < 4; mi++)
#pragma unroll
            for (int ni = 0; ni < 4; ni++)
                acc[mi][ni] = __builtin_amdgcn_mfma_f32_16x16x32_bf16(
                    af[mi], bfm[ni], acc[mi][ni], 0, 0, 0);
    }

    const int fb = ((n0 + wn) >> 1) + (lane & 15);
#pragma unroll
    for (int mi = 0; mi < 4; mi++) {
        const int mrow = moff + m0 + wm + mi * 16 + ((lane >> 4) << 2);
#pragma unroll
        for (int p = 0; p < 2; p++) {
            f32x4 g = acc[mi][2 * p];
            f32x4 u = acc[mi][2 * p + 1];
            const int f = fb + p * 16;
#pragma unroll
            for (int r = 0; r < 4; r++) {
                float gv = g[r];
                float hv = (gv / (1.f + __expf(-gv))) * u[r];
                H[(size_t)(mrow + r) * F_DIM + f] = (unsigned short)f2bf_u(hv);
            }
        }
    }
}

__global__ __launch_bounds__(256)
void legacy_gemm2(const unsigned short* __restrict__ H, const float* __restrict__ w2,
                  const int* __restrict__ counts, const int* __restrict__ tok,
                  float* __restrict__ out)
{
    const int e = blockIdx.z;
    const int cnt = counts[e];
    const int m0 = blockIdx.y * BM;
    if (m0 >= cnt) return;
    const int moff = expert_off(counts, e);
    const int n0 = blockIdx.x * BN;

    const float* W2 = w2 + (size_t)e * D_DIM * F_DIM;
    const int* tk = tok + e * T_TOK;

    __shared__ unsigned short As[BM * LDK];
    __shared__ unsigned short Bs[BN * LDK];

    const int tid = threadIdx.x;
    const int lane = tid & 63, wave = tid >> 6;
    const int wm = (wave >> 1) * 64, wn = (wave & 1) * 64;
    const int sr = tid >> 1, sc = (tid & 1) * 16;

    const unsigned short* arow = H + (size_t)(moff + m0 + sr) * F_DIM + sc;
    const float* brow = W2 + (size_t)(n0 + sr) * F_DIM + sc;

    f32x4 acc[4][4] = {};
    const int ko = (lane >> 4) * 8;
    const int mr = wm + (lane & 15);
    const int nr = wn + (lane & 15);

    for (int k0 = 0; k0 < F_DIM; k0 += BK) {
        uint4 a0 = ((const uint4*)(arow + k0))[0];
        uint4 a1 = ((const uint4*)(arow + k0))[1];
        const float4* bp = (const float4*)(brow + k0);
        float4 b0 = bp[0], b1 = bp[1], b2 = bp[2], b3 = bp[3];
        uint4 pb0, pb1;
        pb0.x = pack2(b0.x, b0.y); pb0.y = pack2(b0.z, b0.w);
        pb0.z = pack2(b1.x, b1.y); pb0.w = pack2(b1.z, b1.w);
        pb1.x = pack2(b2.x, b2.y); pb1.y = pack2(b2.z, b2.w);
        pb1.z = pack2(b3.x, b3.y); pb1.w = pack2(b3.z, b3.w);

        __syncthreads();
        ((uint4*)&As[sr * LDK + sc])[0] = a0;
        ((uint4*)&As[sr * LDK + sc])[1] = a1;
        ((uint4*)&Bs[sr * LDK + sc])[0] = pb0;
        ((uint4*)&Bs[sr * LDK + sc])[1] = pb1;
        __syncthreads();

        bf16x8 af[4], bfm[4];
#pragma unroll
        for (int i = 0; i < 4; i++) {
            af[i]  = *(const bf16x8*)&As[(mr + i * 16) * LDK + ko];
            bfm[i] = *(const bf16x8*)&Bs[(nr + i * 16) * LDK + ko];
        }
#pragma unroll
        for (int mi = 0; mi < 4; mi++)
#pragma unroll
            for (int ni = 0; ni < 4; ni++)
                acc[mi][ni] = __builtin_amdgcn_mfma_f32_16x16x32_bf16(
                    af[mi], bfm[ni], acc[mi][ni], 0, 0, 0);
    }

#pragma unroll
    for (int mi = 0; mi < 4; mi++) {
        const int mbase = m0 + wm + mi * 16 + ((lane >> 4) << 2);
#pragma unroll
        for (int r = 0; r < 4; r++) {
            const int m = mbase + r;
            if (m < cnt) {
                const int t = tk[m] >> 1;
                float* orow = out + (size_t)t * D_DIM + n0 + wn + (lane & 15);
#pragma unroll
                for (int ni = 0; ni < 4; ni++)
                    atomicAdd(orow + ni * 16, acc[mi][ni][r]);
            }
        }
    }
}

// ---------------------------------------------------------------------------
extern "C" void kernel_launch(void* const* d_in, const int* in_sizes, int n_in,
                              void* d_out, int out_size, void* d_ws, size_t ws_size,
                              hipStream_t stream)
{
    const float* x  = (const float*)d_in[0];
    const float* gw = (const float*)d_in[1];
    const float* w1 = (const float*)d_in[2];
    const float* w3 = (const float*)d_in[3];
    const float* w2 = (const float*)d_in[4];
    float* out    = (float*)d_out;
    float* logits = out + (size_t)T_TOK * D_DIM;

    // ws layout (offsets 256-ish aligned, all 16B aligned)
    char* ws = (char*)d_ws;
    int*   counts = (int*)ws;                               // 256 B
    int*   tok    = (int*)(ws + 256);                       // 128 KB
    float* wgt    = (float*)(ws + 131328);                  // 128 KB
    unsigned short* Xe = (unsigned short*)(ws + 262400);    // 18,874,368
    unsigned short* H  = (unsigned short*)(ws + 19136768);  // 66,060,288
    float*          buf = (float*)(ws + 85197056);          // 33,554,432
    unsigned short* W13 = (unsigned short*)(ws + 118751488);// 117,440,512
    unsigned short* W2b = (unsigned short*)(ws + 236192000);// 58,720,256
    const size_t NEED_FULL = 294912256;

    hipMemsetAsync(counts, 0, E_NUM * sizeof(int), stream);
    router<<<T_TOK / 4, 256, 0, stream>>>(x, gw, logits, counts, tok, wgt);
    gather<<<dim3(T_TOK / BM, E_NUM), 256, 0, stream>>>(x, counts, tok, wgt, Xe);

    if (ws_size >= NEED_FULL) {
        conv_w13<<<(E_NUM * (size_t)N13 * D_DIM / 8) / 256, 256, 0, stream>>>(w1, w3, W13);
        conv_w2<<<(E_NUM * (size_t)D_DIM * F_DIM / 8) / 256, 256, 0, stream>>>(w2, W2b);
        gemm1_bf<<<dim3(N13 / BN, T_TOK / BM, E_NUM), 256, 0, stream>>>(Xe, W13, counts, H);
        gemm2_bf<<<dim3(D_DIM / BN, T_TOK / BM, E_NUM), 256, 0, stream>>>(H, W2b, counts, tok, buf);
        combine<<<(T_TOK * D_DIM / 4) / 256, 256, 0, stream>>>(buf, out);
    } else {
        hipMemsetAsync(out, 0, (size_t)T_TOK * D_DIM * sizeof(float), stream);
        legacy_gemm1<<<dim3(N13 / BN, T_TOK / BM, E_NUM), 256, 0, stream>>>(Xe, w1, w3, counts, H);
        legacy_gemm2<<<dim3(D_DIM / BN, T_TOK / BM, E_NUM), 256, 0, stream>>>(H, w2, counts, tok, out);
    }
}